// Round 1
// baseline (759.402 us; speedup 1.0000x reference)
//
#include <hip/hip_runtime.h>
#include <math.h>

#define HW 16384

// ---------------------------------------------------------------------------
// mod[b,c] = 1 + (k_v[:, :192] @ w_kR.T) for c<192, else 1 + (k_v[:,192:] @ w_kI.T)
__global__ __launch_bounds__(256) void mod_kernel(
    const float* __restrict__ kv, const float* __restrict__ wkR,
    const float* __restrict__ wkI, float* __restrict__ mod)
{
  int b = blockIdx.x;
  int c = threadIdx.x;
  const float* kvb = kv + b * 256;
  float s = 0.f;
  if (c < 192) {
    const float* wr = wkR + c * 192;
    for (int j = 0; j < 192; ++j) s += kvb[j] * wr[j];
  } else {
    const float* wi = wkI + (c - 192) * 64;
    for (int j = 0; j < 64; ++j) s += kvb[192 + j] * wi[j];
  }
  mod[b * 256 + c] = 1.f + s;
}

// ---------------------------------------------------------------------------
// Y[b][M,HW] = W[M,K] @ (X[b][c0+k, :] * mod[b,c0+k]) ; BM=BN=128, BK=16, 8x8/thread
__global__ __launch_bounds__(256) void gemm128(
    const float* __restrict__ W, int ldW, int Wbstride,
    const float* __restrict__ X, int c0, int Xbstride,
    const float* __restrict__ mod,
    float* __restrict__ Y, int Ybstride, int K)
{
  int b = blockIdx.z;
  int mt = blockIdx.y;
  int nt = blockIdx.x;
  const float* Wb = W + (size_t)b * Wbstride;
  const float* Xb = X + (size_t)b * Xbstride + (size_t)c0 * HW + nt * 128;
  float* Yb = Y + (size_t)b * Ybstride + (size_t)mt * 128 * HW + nt * 128;

  __shared__ float Ws[16][128];
  __shared__ float Xs[16][128];

  int t = threadIdx.x;
  int wm = t >> 1, wk = (t & 1) * 8;      // W tile load: 2x float4 along k
  int xr = t >> 4, xp = (t & 15) * 8;     // X tile load: 2x float4 along px
  int ty = t >> 4, tx = t & 15;           // compute mapping

  float acc[8][8];
  #pragma unroll
  for (int i = 0; i < 8; ++i)
    #pragma unroll
    for (int j = 0; j < 8; ++j) acc[i][j] = 0.f;

  for (int k0 = 0; k0 < K; k0 += 16) {
    const float* wsrc = Wb + (size_t)(mt * 128 + wm) * ldW + k0 + wk;
    float4 w0 = *(const float4*)(wsrc);
    float4 w1 = *(const float4*)(wsrc + 4);
    float sc = mod ? mod[b * 256 + c0 + k0 + xr] : 1.f;
    const float* xsrc = Xb + (size_t)(k0 + xr) * HW + xp;
    float4 x0 = *(const float4*)(xsrc);
    float4 x1 = *(const float4*)(xsrc + 4);
    __syncthreads();
    Ws[wk + 0][wm] = w0.x;
    Ws[wk + 1][wm] = w0.y;
    Ws[wk + 2][wm] = w0.z;
    Ws[wk + 3][wm] = w0.w;
    Ws[wk + 4][wm] = w1.x;
    Ws[wk + 5][wm] = w1.y;
    Ws[wk + 6][wm] = w1.z;
    Ws[wk + 7][wm] = w1.w;
    x0.x *= sc; x0.y *= sc; x0.z *= sc; x0.w *= sc;
    x1.x *= sc; x1.y *= sc; x1.z *= sc; x1.w *= sc;
    *(float4*)&Xs[xr][xp] = x0;
    *(float4*)&Xs[xr][xp + 4] = x1;
    __syncthreads();
    #pragma unroll
    for (int kk = 0; kk < 16; ++kk) {
      float4 a0 = *(float4*)&Ws[kk][ty * 8];
      float4 a1 = *(float4*)&Ws[kk][ty * 8 + 4];
      float4 b0 = *(float4*)&Xs[kk][tx * 8];
      float4 b1 = *(float4*)&Xs[kk][tx * 8 + 4];
      float av[8] = {a0.x, a0.y, a0.z, a0.w, a1.x, a1.y, a1.z, a1.w};
      float bv[8] = {b0.x, b0.y, b0.z, b0.w, b1.x, b1.y, b1.z, b1.w};
      #pragma unroll
      for (int i = 0; i < 8; ++i)
        #pragma unroll
        for (int j = 0; j < 8; ++j) acc[i][j] += av[i] * bv[j];
    }
  }
  #pragma unroll
  for (int i = 0; i < 8; ++i) {
    float* yr = Yb + (size_t)(ty * 8 + i) * HW + tx * 8;
    *(float4*)yr = make_float4(acc[i][0], acc[i][1], acc[i][2], acc[i][3]);
    *(float4*)(yr + 4) = make_float4(acc[i][4], acc[i][5], acc[i][6], acc[i][7]);
  }
}

// ---------------------------------------------------------------------------
// depthwise 3x3, SAME zero pad; optional per-channel sum-of-squares accumulation
__global__ __launch_bounds__(256) void dwconv_kernel(
    const float* __restrict__ in, const float* __restrict__ wdw,
    float* __restrict__ out, float* __restrict__ ssq)
{
  int t = threadIdx.x;
  int x = t & 127, yl = t >> 7;
  int c = blockIdx.y, b = blockIdx.z;
  const float* ip = in + (((size_t)b * 256 + c) << 14);
  float* op = out + (((size_t)b * 256 + c) << 14);
  const float* wp = wdw + c * 9;
  float w0 = wp[0], w1 = wp[1], w2 = wp[2], w3 = wp[3], w4 = wp[4],
        w5 = wp[5], w6 = wp[6], w7 = wp[7], w8 = wp[8];
  bool oxm = x > 0, oxp = x < 127;
  float ss = 0.f;
  #pragma unroll
  for (int it = 0; it < 4; ++it) {
    int y = blockIdx.x * 8 + it * 2 + yl;
    int ym = y - 1, yp2 = y + 1;
    const float* r1 = ip + (y << 7);
    float s = 0.f;
    if (ym >= 0) {
      const float* r0 = ip + (ym << 7);
      if (oxm) s += r0[x - 1] * w0;
      s += r0[x] * w1;
      if (oxp) s += r0[x + 1] * w2;
    }
    if (oxm) s += r1[x - 1] * w3;
    s += r1[x] * w4;
    if (oxp) s += r1[x + 1] * w5;
    if (yp2 < 128) {
      const float* r2 = ip + (yp2 << 7);
      if (oxm) s += r2[x - 1] * w6;
      s += r2[x] * w7;
      if (oxp) s += r2[x + 1] * w8;
    }
    op[(y << 7) + x] = s;
    ss += s * s;
  }
  if (ssq) {
    #pragma unroll
    for (int off = 32; off > 0; off >>= 1) ss += __shfl_down(ss, off);
    if ((t & 63) == 0) atomicAdd(&ssq[b * 256 + c], ss);
  }
}

// ---------------------------------------------------------------------------
// S[b,h,c,d] += sum_p qdw[b,h*32+c,p] * kdw[b,h*32+d,p]  (unnormalized Gram)
__global__ __launch_bounds__(256) void gram_kernel(
    const float* __restrict__ qdw, const float* __restrict__ kdw,
    float* __restrict__ S)
{
  int chunk = blockIdx.x, h = blockIdx.y, b = blockIdx.z;
  __shared__ float Qs[32][68];
  __shared__ float Ks[32][68];
  int t = threadIdx.x;
  int wave = t >> 6, lane = t & 63;
  int c0 = lane >> 3, d0 = lane & 7;   // c-values {c0+8i}, d-values {d0+8j}
  float acc[4][4];
  #pragma unroll
  for (int i = 0; i < 4; ++i)
    #pragma unroll
    for (int j = 0; j < 4; ++j) acc[i][j] = 0.f;

  const float* qb = qdw + (((size_t)b * 256 + h * 32) << 14) + chunk * 1024;
  const float* kb = kdw + (((size_t)b * 256 + h * 32) << 14) + chunk * 1024;
  int lch = t >> 4;           // 0..15 (second half +16)
  int lpx = (t & 15) << 2;    // 0..60

  for (int sub = 0; sub < 16; ++sub) {
    float4 qa = *(const float4*)(qb + ((size_t)lch << 14) + sub * 64 + lpx);
    float4 qc = *(const float4*)(qb + ((size_t)(lch + 16) << 14) + sub * 64 + lpx);
    float4 ka = *(const float4*)(kb + ((size_t)lch << 14) + sub * 64 + lpx);
    float4 kc = *(const float4*)(kb + ((size_t)(lch + 16) << 14) + sub * 64 + lpx);
    __syncthreads();
    *(float4*)&Qs[lch][lpx] = qa;
    *(float4*)&Qs[lch + 16][lpx] = qc;
    *(float4*)&Ks[lch][lpx] = ka;
    *(float4*)&Ks[lch + 16][lpx] = kc;
    __syncthreads();
    #pragma unroll
    for (int pg = 0; pg < 4; ++pg) {
      int p0 = (wave << 4) + (pg << 2);
      float4 q0 = *(float4*)&Qs[c0][p0];
      float4 q1 = *(float4*)&Qs[c0 + 8][p0];
      float4 q2 = *(float4*)&Qs[c0 + 16][p0];
      float4 q3 = *(float4*)&Qs[c0 + 24][p0];
      float4 k0v = *(float4*)&Ks[d0][p0];
      float4 k1v = *(float4*)&Ks[d0 + 8][p0];
      float4 k2v = *(float4*)&Ks[d0 + 16][p0];
      float4 k3v = *(float4*)&Ks[d0 + 24][p0];
      float qv[4][4] = {{q0.x, q0.y, q0.z, q0.w}, {q1.x, q1.y, q1.z, q1.w},
                        {q2.x, q2.y, q2.z, q2.w}, {q3.x, q3.y, q3.z, q3.w}};
      float kv[4][4] = {{k0v.x, k0v.y, k0v.z, k0v.w}, {k1v.x, k1v.y, k1v.z, k1v.w},
                        {k2v.x, k2v.y, k2v.z, k2v.w}, {k3v.x, k3v.y, k3v.z, k3v.w}};
      #pragma unroll
      for (int i = 0; i < 4; ++i)
        #pragma unroll
        for (int j = 0; j < 4; ++j)
          acc[i][j] += qv[i][0] * kv[j][0] + qv[i][1] * kv[j][1] +
                       qv[i][2] * kv[j][2] + qv[i][3] * kv[j][3];
    }
  }
  float* Sp = S + (((size_t)b * 8 + h) << 10);
  #pragma unroll
  for (int i = 0; i < 4; ++i)
    #pragma unroll
    for (int j = 0; j < 4; ++j)
      atomicAdd(&Sp[(c0 + 8 * i) * 32 + d0 + 8 * j], acc[i][j]);
}

// ---------------------------------------------------------------------------
// in-place: S <- softmax_d( S / (max(|q|,eps)*max(|k|,eps)) * temp[h] )
__global__ __launch_bounds__(64) void softmax_kernel(
    float* __restrict__ S, const float* __restrict__ ssq,
    const float* __restrict__ ssk, const float* __restrict__ temp)
{
  int bh = blockIdx.x;
  int b = bh >> 3, h = bh & 7;
  int c = threadIdx.x;
  if (c >= 32) return;
  float* row = S + ((size_t)bh << 10) + c * 32;
  float invq = 1.f / fmaxf(sqrtf(ssq[b * 256 + h * 32 + c]), 1e-12f);
  float T = temp[h];
  float lg[32];
  float mx = -1e30f;
  for (int d = 0; d < 32; ++d) {
    float invk = 1.f / fmaxf(sqrtf(ssk[b * 256 + h * 32 + d]), 1e-12f);
    float v = row[d] * invq * invk * T;
    lg[d] = v;
    mx = fmaxf(mx, v);
  }
  float sum = 0.f;
  for (int d = 0; d < 32; ++d) { float e = expf(lg[d] - mx); lg[d] = e; sum += e; }
  float inv = 1.f / sum;
  for (int d = 0; d < 32; ++d) row[d] = lg[d] * inv;
}

// ---------------------------------------------------------------------------
// M[b][o][h*32+d] = sum_c w_proj[o][h*32+c] * attn[b,h,c,d]
__global__ __launch_bounds__(256) void mbuild_kernel(
    const float* __restrict__ attn, const float* __restrict__ wproj,
    float* __restrict__ M)
{
  int o = blockIdx.x, b = blockIdx.y;
  int col = threadIdx.x;
  int h = col >> 5, d = col & 31;
  const float* a = attn + (((size_t)b * 8 + h) << 10);
  const float* wp = wproj + o * 256 + h * 32;
  float s = 0.f;
  #pragma unroll
  for (int cc = 0; cc < 32; ++cc) s += wp[cc] * a[cc * 32 + d];
  M[((size_t)b * 256 + o) * 256 + col] = s;
}

// ---------------------------------------------------------------------------
extern "C" void kernel_launch(void* const* d_in, const int* in_sizes, int n_in,
                              void* d_out, int out_size, void* d_ws, size_t ws_size,
                              hipStream_t stream)
{
  const float* x      = (const float*)d_in[0];
  const float* k_v    = (const float*)d_in[1];
  const float* temp   = (const float*)d_in[2];
  const float* w_kR   = (const float*)d_in[3];
  const float* w_kI   = (const float*)d_in[4];
  const float* w_qR   = (const float*)d_in[5];
  const float* w_qdw  = (const float*)d_in[6];
  const float* w_kvI  = (const float*)d_in[7];
  const float* w_kvdw = (const float*)d_in[8];
  const float* w_proj = (const float*)d_in[9];
  float* out = (float*)d_out;

  float* ws   = (float*)d_ws;
  float* bufA = ws;                 // 64 MB
  float* bufB = ws + 16777216;      // 64 MB
  float* bufC = ws + 33554432;      // 64 MB
  float* sm   = ws + 50331648;      // small region at 192 MB
  float* mod  = sm;                 // 1024
  float* ssq  = sm + 1024;          // 1024 (q norms^2)
  float* ssk  = sm + 2048;          // 1024 (k norms^2)
  float* S    = sm + 3072;          // 32768 (Gram -> attn in place)
  float* M    = sm + 3072 + 32768;  // 262144 (fused attn+proj matrix)

  // zero the atomically-accumulated buffers (ws is poisoned each call)
  hipMemsetAsync(ssq, 0, (size_t)(1024 + 1024 + 32768) * sizeof(float), stream);

  mod_kernel<<<dim3(4), dim3(256), 0, stream>>>(k_v, w_kR, w_kI, mod);

  // k_pre -> bufA ; kdw -> bufB (+ k norms)
  gemm128<<<dim3(128, 2, 4), dim3(256), 0, stream>>>(
      w_kvI, 64, 0, x, 192, 4194304, mod, bufA, 4194304, 64);
  dwconv_kernel<<<dim3(16, 256, 4), dim3(256), 0, stream>>>(bufA, w_kvdw, bufB, ssk);

  // q_pre -> bufA ; qdw -> bufC (+ q norms)
  gemm128<<<dim3(128, 2, 4), dim3(256), 0, stream>>>(
      w_qR, 192, 0, x, 0, 4194304, mod, bufA, 4194304, 192);
  dwconv_kernel<<<dim3(16, 256, 4), dim3(256), 0, stream>>>(bufA, w_qdw, bufC, ssq);

  // Gram: S = qdw . kdw^T over pixels
  gram_kernel<<<dim3(16, 8, 4), dim3(256), 0, stream>>>(bufC, bufB, S);

  // v_pre -> bufA (bufA free after q dwconv)
  gemm128<<<dim3(128, 2, 4), dim3(256), 0, stream>>>(
      w_kvI + 256 * 64, 64, 0, x, 192, 4194304, mod, bufA, 4194304, 64);

  // attn (in place on S), then M = w_proj @ blockdiag(attn)
  softmax_kernel<<<dim3(32), dim3(64), 0, stream>>>(S, ssq, ssk, temp);
  mbuild_kernel<<<dim3(256, 4), dim3(256), 0, stream>>>(S, w_proj, M);

  // vdw -> bufC (bufC free after gram)
  dwconv_kernel<<<dim3(16, 256, 4), dim3(256), 0, stream>>>(
      bufA, w_kvdw + 256 * 9, bufC, (float*)nullptr);

  // out = M[b] @ vdw[b]
  gemm128<<<dim3(128, 2, 4), dim3(256), 0, stream>>>(
      M, 256, 65536, bufC, 0, 4194304, (const float*)nullptr, out, 4194304, 256);
}

// Round 2
// 500.953 us; speedup vs baseline: 1.5159x; 1.5159x over previous
//
#include <hip/hip_runtime.h>
#include <math.h>

#define HW 16384

// ---------------------------------------------------------------------------
// mod[b,c] = 1 + (k_v[:, :192] @ w_kR.T) for c<192, else 1 + (k_v[:,192:] @ w_kI.T)
__global__ __launch_bounds__(256) void mod_kernel(
    const float* __restrict__ kv, const float* __restrict__ wkR,
    const float* __restrict__ wkI, float* __restrict__ mod)
{
  int b = blockIdx.x;
  int c = threadIdx.x;
  const float* kvb = kv + b * 256;
  float s = 0.f;
  if (c < 192) {
    const float* wr = wkR + c * 192;
    for (int j = 0; j < 192; ++j) s += kvb[j] * wr[j];
  } else {
    const float* wi = wkI + (c - 192) * 64;
    for (int j = 0; j < 64; ++j) s += kvb[192 + j] * wi[j];
  }
  mod[b * 256 + c] = 1.f + s;
}

// ---------------------------------------------------------------------------
// Y[b][M,HW] = W[M,K] @ (X[b][c0+k, :] * mod[b,c0+k]) ; BM=BN=128, BK=16, 8x8/thread
__global__ __launch_bounds__(256) void gemm128(
    const float* __restrict__ W, int ldW, int Wbstride,
    const float* __restrict__ X, int c0, int Xbstride,
    const float* __restrict__ mod,
    float* __restrict__ Y, int Ybstride, int K)
{
  int b = blockIdx.z;
  int mt = blockIdx.y;
  int nt = blockIdx.x;
  const float* Wb = W + (size_t)b * Wbstride;
  const float* Xb = X + (size_t)b * Xbstride + (size_t)c0 * HW + nt * 128;
  float* Yb = Y + (size_t)b * Ybstride + (size_t)mt * 128 * HW + nt * 128;

  __shared__ float Ws[16][128];
  __shared__ float Xs[16][128];

  int t = threadIdx.x;
  int wm = t >> 1, wk = (t & 1) * 8;      // W tile load: 2x float4 along k
  int xr = t >> 4, xp = (t & 15) * 8;     // X tile load: 2x float4 along px
  int ty = t >> 4, tx = t & 15;           // compute mapping

  float acc[8][8];
  #pragma unroll
  for (int i = 0; i < 8; ++i)
    #pragma unroll
    for (int j = 0; j < 8; ++j) acc[i][j] = 0.f;

  for (int k0 = 0; k0 < K; k0 += 16) {
    const float* wsrc = Wb + (size_t)(mt * 128 + wm) * ldW + k0 + wk;
    float4 w0 = *(const float4*)(wsrc);
    float4 w1 = *(const float4*)(wsrc + 4);
    float sc = mod ? mod[b * 256 + c0 + k0 + xr] : 1.f;
    const float* xsrc = Xb + (size_t)(k0 + xr) * HW + xp;
    float4 x0 = *(const float4*)(xsrc);
    float4 x1 = *(const float4*)(xsrc + 4);
    __syncthreads();
    Ws[wk + 0][wm] = w0.x;
    Ws[wk + 1][wm] = w0.y;
    Ws[wk + 2][wm] = w0.z;
    Ws[wk + 3][wm] = w0.w;
    Ws[wk + 4][wm] = w1.x;
    Ws[wk + 5][wm] = w1.y;
    Ws[wk + 6][wm] = w1.z;
    Ws[wk + 7][wm] = w1.w;
    x0.x *= sc; x0.y *= sc; x0.z *= sc; x0.w *= sc;
    x1.x *= sc; x1.y *= sc; x1.z *= sc; x1.w *= sc;
    *(float4*)&Xs[xr][xp] = x0;
    *(float4*)&Xs[xr][xp + 4] = x1;
    __syncthreads();
    #pragma unroll
    for (int kk = 0; kk < 16; ++kk) {
      float4 a0 = *(float4*)&Ws[kk][ty * 8];
      float4 a1 = *(float4*)&Ws[kk][ty * 8 + 4];
      float4 b0 = *(float4*)&Xs[kk][tx * 8];
      float4 b1 = *(float4*)&Xs[kk][tx * 8 + 4];
      float av[8] = {a0.x, a0.y, a0.z, a0.w, a1.x, a1.y, a1.z, a1.w};
      float bv[8] = {b0.x, b0.y, b0.z, b0.w, b1.x, b1.y, b1.z, b1.w};
      #pragma unroll
      for (int i = 0; i < 8; ++i)
        #pragma unroll
        for (int j = 0; j < 8; ++j) acc[i][j] += av[i] * bv[j];
    }
  }
  #pragma unroll
  for (int i = 0; i < 8; ++i) {
    float* yr = Yb + (size_t)(ty * 8 + i) * HW + tx * 8;
    *(float4*)yr = make_float4(acc[i][0], acc[i][1], acc[i][2], acc[i][3]);
    *(float4*)(yr + 4) = make_float4(acc[i][4], acc[i][5], acc[i][6], acc[i][7]);
  }
}

// ---------------------------------------------------------------------------
// depthwise 3x3, SAME zero pad. One block per (channel, batch): 256 threads,
// thread-row r (0..7) covers y in [16r,16r+16), each thread 4 x-pixels (float4).
// Sliding 3-row register window; x+-1 halo via __shfl within the 32-lane row.
// ssq (if non-null) gets the per-channel sum of squares via block reduction
// (plain store — no atomics, no memset needed).
__global__ __launch_bounds__(256) void dwconv_kernel(
    const float* __restrict__ in, size_t in_bstride,
    const float* __restrict__ wdw,
    float* __restrict__ out, size_t out_bstride,
    float* __restrict__ ssq)
{
  int c = blockIdx.x;
  int b = blockIdx.y;
  int t = threadIdx.x;
  int r = t >> 5;      // thread-row 0..7
  int xq = t & 31;     // float4 column within the 128-px row

  const float4* ip4 = (const float4*)(in + (size_t)b * in_bstride + ((size_t)c << 14));
  float4* op4 = (float4*)(out + (size_t)b * out_bstride + ((size_t)c << 14));
  const float* wp = wdw + c * 9;
  float w0 = wp[0], w1 = wp[1], w2 = wp[2], w3 = wp[3], w4 = wp[4],
        w5 = wp[5], w6 = wp[6], w7 = wp[7], w8 = wp[8];

  const float4 z4 = make_float4(0.f, 0.f, 0.f, 0.f);
  int y0 = r << 4;

  float4 a = (y0 > 0) ? ip4[((y0 - 1) << 5) + xq] : z4;
  float4 bb = ip4[(y0 << 5) + xq];

  float aL = __shfl_up(a.w, 1);  if (xq == 0)  aL = 0.f;
  float aR = __shfl_down(a.x, 1); if (xq == 31) aR = 0.f;
  float bL = __shfl_up(bb.w, 1); if (xq == 0)  bL = 0.f;
  float bR = __shfl_down(bb.x, 1); if (xq == 31) bR = 0.f;

  float ss = 0.f;
  #pragma unroll
  for (int i = 0; i < 16; ++i) {
    int y = y0 + i;
    int yc = (y + 1 < 128) ? (y + 1) : 127;   // clamped (uniform) load
    float4 cc = ip4[(yc << 5) + xq];
    if (y + 1 >= 128) { cc.x = 0.f; cc.y = 0.f; cc.z = 0.f; cc.w = 0.f; }
    float cL = __shfl_up(cc.w, 1);  if (xq == 0)  cL = 0.f;
    float cR = __shfl_down(cc.x, 1); if (xq == 31) cR = 0.f;

    float4 o;
    o.x = w0 * aL  + w1 * a.x + w2 * a.y +
          w3 * bL  + w4 * bb.x + w5 * bb.y +
          w6 * cL  + w7 * cc.x + w8 * cc.y;
    o.y = w0 * a.x + w1 * a.y + w2 * a.z +
          w3 * bb.x + w4 * bb.y + w5 * bb.z +
          w6 * cc.x + w7 * cc.y + w8 * cc.z;
    o.z = w0 * a.y + w1 * a.z + w2 * a.w +
          w3 * bb.y + w4 * bb.z + w5 * bb.w +
          w6 * cc.y + w7 * cc.z + w8 * cc.w;
    o.w = w0 * a.z + w1 * a.w + w2 * aR +
          w3 * bb.z + w4 * bb.w + w5 * bR +
          w6 * cc.z + w7 * cc.w + w8 * cR;

    op4[(y << 5) + xq] = o;
    ss += o.x * o.x + o.y * o.y + o.z * o.z + o.w * o.w;

    a = bb; aL = bL; aR = bR;
    bb = cc; bL = cL; bR = cR;
  }

  if (ssq) {
    #pragma unroll
    for (int off = 32; off > 0; off >>= 1) ss += __shfl_down(ss, off);
    __shared__ float red[4];
    if ((t & 63) == 0) red[t >> 6] = ss;
    __syncthreads();
    if (t == 0) ssq[b * 256 + c] = red[0] + red[1] + red[2] + red[3];
  }
}

// ---------------------------------------------------------------------------
// S[b,h,c,d] += sum_p qdw[b,h*32+c,p] * kdw[b,h*32+d,p]  (unnormalized Gram)
__global__ __launch_bounds__(256) void gram_kernel(
    const float* __restrict__ qdw, const float* __restrict__ kdw,
    float* __restrict__ S)
{
  int chunk = blockIdx.x, h = blockIdx.y, b = blockIdx.z;
  __shared__ float Qs[32][68];
  __shared__ float Ks[32][68];
  int t = threadIdx.x;
  int wave = t >> 6, lane = t & 63;
  int c0 = lane >> 3, d0 = lane & 7;   // c-values {c0+8i}, d-values {d0+8j}
  float acc[4][4];
  #pragma unroll
  for (int i = 0; i < 4; ++i)
    #pragma unroll
    for (int j = 0; j < 4; ++j) acc[i][j] = 0.f;

  const float* qb = qdw + (((size_t)b * 256 + h * 32) << 14) + chunk * 1024;
  const float* kb = kdw + (((size_t)b * 256 + h * 32) << 14) + chunk * 1024;
  int lch = t >> 4;           // 0..15 (second half +16)
  int lpx = (t & 15) << 2;    // 0..60

  for (int sub = 0; sub < 16; ++sub) {
    float4 qa = *(const float4*)(qb + ((size_t)lch << 14) + sub * 64 + lpx);
    float4 qc = *(const float4*)(qb + ((size_t)(lch + 16) << 14) + sub * 64 + lpx);
    float4 ka = *(const float4*)(kb + ((size_t)lch << 14) + sub * 64 + lpx);
    float4 kc = *(const float4*)(kb + ((size_t)(lch + 16) << 14) + sub * 64 + lpx);
    __syncthreads();
    *(float4*)&Qs[lch][lpx] = qa;
    *(float4*)&Qs[lch + 16][lpx] = qc;
    *(float4*)&Ks[lch][lpx] = ka;
    *(float4*)&Ks[lch + 16][lpx] = kc;
    __syncthreads();
    #pragma unroll
    for (int pg = 0; pg < 4; ++pg) {
      int p0 = (wave << 4) + (pg << 2);
      float4 q0 = *(float4*)&Qs[c0][p0];
      float4 q1 = *(float4*)&Qs[c0 + 8][p0];
      float4 q2 = *(float4*)&Qs[c0 + 16][p0];
      float4 q3 = *(float4*)&Qs[c0 + 24][p0];
      float4 k0v = *(float4*)&Ks[d0][p0];
      float4 k1v = *(float4*)&Ks[d0 + 8][p0];
      float4 k2v = *(float4*)&Ks[d0 + 16][p0];
      float4 k3v = *(float4*)&Ks[d0 + 24][p0];
      float qv[4][4] = {{q0.x, q0.y, q0.z, q0.w}, {q1.x, q1.y, q1.z, q1.w},
                        {q2.x, q2.y, q2.z, q2.w}, {q3.x, q3.y, q3.z, q3.w}};
      float kv[4][4] = {{k0v.x, k0v.y, k0v.z, k0v.w}, {k1v.x, k1v.y, k1v.z, k1v.w},
                        {k2v.x, k2v.y, k2v.z, k2v.w}, {k3v.x, k3v.y, k3v.z, k3v.w}};
      #pragma unroll
      for (int i = 0; i < 4; ++i)
        #pragma unroll
        for (int j = 0; j < 4; ++j)
          acc[i][j] += qv[i][0] * kv[j][0] + qv[i][1] * kv[j][1] +
                       qv[i][2] * kv[j][2] + qv[i][3] * kv[j][3];
    }
  }
  float* Sp = S + (((size_t)b * 8 + h) << 10);
  #pragma unroll
  for (int i = 0; i < 4; ++i)
    #pragma unroll
    for (int j = 0; j < 4; ++j)
      atomicAdd(&Sp[(c0 + 8 * i) * 32 + d0 + 8 * j], acc[i][j]);
}

// ---------------------------------------------------------------------------
// in-place: S <- softmax_d( S / (max(|q|,eps)*max(|k|,eps)) * temp[h] )
__global__ __launch_bounds__(64) void softmax_kernel(
    float* __restrict__ S, const float* __restrict__ ssq,
    const float* __restrict__ ssk, const float* __restrict__ temp)
{
  int bh = blockIdx.x;
  int b = bh >> 3, h = bh & 7;
  int c = threadIdx.x;
  if (c >= 32) return;
  float* row = S + ((size_t)bh << 10) + c * 32;
  float invq = 1.f / fmaxf(sqrtf(ssq[b * 256 + h * 32 + c]), 1e-12f);
  float T = temp[h];
  float lg[32];
  float mx = -1e30f;
  for (int d = 0; d < 32; ++d) {
    float invk = 1.f / fmaxf(sqrtf(ssk[b * 256 + h * 32 + d]), 1e-12f);
    float v = row[d] * invq * invk * T;
    lg[d] = v;
    mx = fmaxf(mx, v);
  }
  float sum = 0.f;
  for (int d = 0; d < 32; ++d) { float e = expf(lg[d] - mx); lg[d] = e; sum += e; }
  float inv = 1.f / sum;
  for (int d = 0; d < 32; ++d) row[d] = lg[d] * inv;
}

// ---------------------------------------------------------------------------
// M[b][o][h*32+d] = sum_c w_proj[o][h*32+c] * attn[b,h,c,d]
__global__ __launch_bounds__(256) void mbuild_kernel(
    const float* __restrict__ attn, const float* __restrict__ wproj,
    float* __restrict__ M)
{
  int o = blockIdx.x, b = blockIdx.y;
  int col = threadIdx.x;
  int h = col >> 5, d = col & 31;
  const float* a = attn + (((size_t)b * 8 + h) << 10);
  const float* wp = wproj + o * 256 + h * 32;
  float s = 0.f;
  #pragma unroll
  for (int cc = 0; cc < 32; ++cc) s += wp[cc] * a[cc * 32 + d];
  M[((size_t)b * 256 + o) * 256 + col] = s;
}

// ---------------------------------------------------------------------------
extern "C" void kernel_launch(void* const* d_in, const int* in_sizes, int n_in,
                              void* d_out, int out_size, void* d_ws, size_t ws_size,
                              hipStream_t stream)
{
  const float* x      = (const float*)d_in[0];
  const float* k_v    = (const float*)d_in[1];
  const float* temp   = (const float*)d_in[2];
  const float* w_kR   = (const float*)d_in[3];
  const float* w_kI   = (const float*)d_in[4];
  const float* w_qR   = (const float*)d_in[5];
  const float* w_qdw  = (const float*)d_in[6];
  const float* w_kvI  = (const float*)d_in[7];
  const float* w_kvdw = (const float*)d_in[8];
  const float* w_proj = (const float*)d_in[9];
  float* out = (float*)d_out;

  float* ws   = (float*)d_ws;
  float* bufA = ws;                 // 64 MB
  float* bufB = ws + 16777216;      // 64 MB
  float* bufC = ws + 33554432;      // 64 MB
  float* sm   = ws + 50331648;      // small region at 192 MB
  float* mod  = sm;                 // 1024
  float* ssq  = sm + 1024;          // 1024 (q norms^2, plain store)
  float* ssk  = sm + 2048;          // 1024 (k norms^2, plain store)
  float* S    = sm + 3072;          // 32768 (Gram -> attn in place)
  float* M    = sm + 3072 + 32768;  // 262144 (fused attn+proj matrix)

  // zero only the atomically-accumulated Gram buffer (ws is poisoned each call)
  hipMemsetAsync(S, 0, (size_t)32768 * sizeof(float), stream);

  mod_kernel<<<dim3(4), dim3(256), 0, stream>>>(k_v, w_kR, w_kI, mod);

  // k_pre -> bufA ; kdw -> bufB (+ k norms)
  gemm128<<<dim3(128, 2, 4), dim3(256), 0, stream>>>(
      w_kvI, 64, 0, x, 192, 4194304, mod, bufA, 4194304, 64);
  dwconv_kernel<<<dim3(256, 4), dim3(256), 0, stream>>>(
      bufA, 4194304, w_kvdw, bufB, 4194304, ssk);

  // q_pre -> bufA ; qdw -> bufC (+ q norms)
  gemm128<<<dim3(128, 2, 4), dim3(256), 0, stream>>>(
      w_qR, 192, 0, x, 0, 4194304, mod, bufA, 4194304, 192);
  dwconv_kernel<<<dim3(256, 4), dim3(256), 0, stream>>>(
      bufA, 4194304, w_qdw, bufC, 4194304, ssq);

  // Gram: S = qdw . kdw^T over pixels
  gram_kernel<<<dim3(16, 8, 4), dim3(256), 0, stream>>>(bufC, bufB, S);

  // v_pre -> bufA (bufA free after q dwconv)
  gemm128<<<dim3(128, 2, 4), dim3(256), 0, stream>>>(
      w_kvI + 256 * 64, 64, 0, x, 192, 4194304, mod, bufA, 4194304, 64);

  // attn (in place on S), then M = w_proj @ blockdiag(attn)
  softmax_kernel<<<dim3(32), dim3(64), 0, stream>>>(S, ssq, ssk, temp);
  mbuild_kernel<<<dim3(256, 4), dim3(256), 0, stream>>>(S, w_proj, M);

  // vdw -> bufC (bufC free after gram)
  dwconv_kernel<<<dim3(256, 4), dim3(256), 0, stream>>>(
      bufA, 4194304, w_kvdw + 256 * 9, bufC, 4194304, (float*)nullptr);

  // out = M[b] @ vdw[b]
  gemm128<<<dim3(128, 2, 4), dim3(256), 0, stream>>>(
      M, 256, 65536, bufC, 0, 4194304, (const float*)nullptr, out, 4194304, 256);
}

// Round 3
// 335.383 us; speedup vs baseline: 2.2643x; 1.4937x over previous
//
#include <hip/hip_runtime.h>
#include <math.h>

#define HW 16384

typedef unsigned int uint;
typedef short bfrag __attribute__((ext_vector_type(8)));   // 8 bf16 (4 VGPRs)
typedef float f32x4 __attribute__((ext_vector_type(4)));   // 4 fp32 acc

union FragCvt { uint4 u; bfrag v; };

// round-to-nearest-even f32 -> bf16, pack two into a dword
__device__ inline uint pack2bf(float a, float b) {
  uint ua = __builtin_bit_cast(uint, a);
  uint ub = __builtin_bit_cast(uint, b);
  ua = (ua + 0x7FFFu + ((ua >> 16) & 1u)) >> 16;
  ub = (ub + 0x7FFFu + ((ub >> 16) & 1u)) & 0xFFFF0000u;
  return ua | ub;
}

// ---------------------------------------------------------------------------
// mod[b,c] = 1 + (k_v[:, :192] @ w_kR.T) for c<192, else 1 + (k_v[:,192:] @ w_kI.T)
__global__ __launch_bounds__(256) void mod_kernel(
    const float* __restrict__ kv, const float* __restrict__ wkR,
    const float* __restrict__ wkI, float* __restrict__ mod)
{
  int b = blockIdx.x;
  int c = threadIdx.x;
  const float* kvb = kv + b * 256;
  float s = 0.f;
  if (c < 192) {
    const float* wr = wkR + c * 192;
    for (int j = 0; j < 192; ++j) s += kvb[j] * wr[j];
  } else {
    const float* wi = wkI + (c - 192) * 64;
    for (int j = 0; j < 64; ++j) s += kvb[192 + j] * wi[j];
  }
  mod[b * 256 + c] = 1.f + s;
}

// ---------------------------------------------------------------------------
// bf16-MFMA GEMM: Y[b][M,HW] = W[M,K] @ (X[b][c0+k,:] * mod[b,c0+k])
// 128x128 tile, BK=32, 256 threads = 4 waves (2x2 of 64x64), 4x4 frags of
// 16x16x32. f32 inputs converted RNE->bf16 during LDS staging; f32 accum.
// LDS layout [row][k] with k-stride 40 bf16 (80 B): 16B-aligned b128 frags,
// 2 lanes/bank (free). A = W rows, B stored as [pixel][k].
__global__ __launch_bounds__(256) void mgemm(
    const float* __restrict__ W, int ldW, size_t Wbstride,
    const float* __restrict__ X, int c0, size_t Xbstride,
    const float* __restrict__ mod,
    float* __restrict__ Y, size_t Ybstride, int K)
{
  int b = blockIdx.z, mt = blockIdx.y, nt = blockIdx.x;
  const float* Wb = W + (size_t)b * Wbstride + (size_t)mt * 128 * ldW;
  const float* Xb = X + (size_t)b * Xbstride + (size_t)c0 * HW + nt * 128;
  float* Yb = Y + (size_t)b * Ybstride + (size_t)mt * 128 * HW + nt * 128;

  __shared__ unsigned short Al[128 * 40];
  __shared__ unsigned short Bl[128 * 40];

  int t = threadIdx.x;
  int w = t >> 6, l = t & 63;
  int wm = (w >> 1) * 64, wn = (w & 1) * 64;
  int lm = l & 15, lk = (l >> 4) * 8;

  int am = t >> 1, ako = (t & 1) * 16;     // A staging: row, k-offset (16 f32)
  int bn = t & 127, bo = (t >> 7) * 8;     // B staging: pixel, k-octet base

  f32x4 acc[4][4];
  #pragma unroll
  for (int fi = 0; fi < 4; ++fi)
    #pragma unroll
    for (int fj = 0; fj < 4; ++fj) acc[fi][fj] = {0.f, 0.f, 0.f, 0.f};

  for (int k0 = 0; k0 < K; k0 += 32) {
    // ---- global loads into registers
    const float* wsrc = Wb + (size_t)am * ldW + k0 + ako;
    float4 a0 = *(const float4*)(wsrc);
    float4 a1 = *(const float4*)(wsrc + 4);
    float4 a2 = *(const float4*)(wsrc + 8);
    float4 a3 = *(const float4*)(wsrc + 12);

    float xr[2][8];
    #pragma unroll
    for (int i = 0; i < 2; ++i) {
      int kb = k0 + bo + i * 16;
      #pragma unroll
      for (int r = 0; r < 8; ++r)
        xr[i][r] = Xb[(size_t)(kb + r) * HW + bn];
    }
    float sc[2][8];
    if (mod) {
      const float* mp = mod + b * 256 + c0 + k0 + bo;
      #pragma unroll
      for (int i = 0; i < 2; ++i) {
        float4 m0 = *(const float4*)(mp + i * 16);
        float4 m1 = *(const float4*)(mp + i * 16 + 4);
        sc[i][0] = m0.x; sc[i][1] = m0.y; sc[i][2] = m0.z; sc[i][3] = m0.w;
        sc[i][4] = m1.x; sc[i][5] = m1.y; sc[i][6] = m1.z; sc[i][7] = m1.w;
      }
    } else {
      #pragma unroll
      for (int i = 0; i < 2; ++i)
        #pragma unroll
        for (int r = 0; r < 8; ++r) sc[i][r] = 1.f;
    }

    __syncthreads();   // previous iteration's LDS reads done

    // ---- stage A (convert to bf16)
    uint4 aw0, aw1;
    aw0.x = pack2bf(a0.x, a0.y); aw0.y = pack2bf(a0.z, a0.w);
    aw0.z = pack2bf(a1.x, a1.y); aw0.w = pack2bf(a1.z, a1.w);
    aw1.x = pack2bf(a2.x, a2.y); aw1.y = pack2bf(a2.z, a2.w);
    aw1.z = pack2bf(a3.x, a3.y); aw1.w = pack2bf(a3.z, a3.w);
    *(uint4*)&Al[am * 40 + ako] = aw0;
    *(uint4*)&Al[am * 40 + ako + 8] = aw1;

    // ---- stage B (mod-scale + convert)
    #pragma unroll
    for (int i = 0; i < 2; ++i) {
      uint4 bw;
      bw.x = pack2bf(xr[i][0] * sc[i][0], xr[i][1] * sc[i][1]);
      bw.y = pack2bf(xr[i][2] * sc[i][2], xr[i][3] * sc[i][3]);
      bw.z = pack2bf(xr[i][4] * sc[i][4], xr[i][5] * sc[i][5]);
      bw.w = pack2bf(xr[i][6] * sc[i][6], xr[i][7] * sc[i][7]);
      *(uint4*)&Bl[bn * 40 + bo + i * 16] = bw;
    }

    __syncthreads();

    // ---- fragments + MFMA
    bfrag af[4], bfr[4];
    #pragma unroll
    for (int fi = 0; fi < 4; ++fi) {
      FragCvt cv;
      cv.u = *(const uint4*)&Al[(wm + fi * 16 + lm) * 40 + lk];
      af[fi] = cv.v;
    }
    #pragma unroll
    for (int fj = 0; fj < 4; ++fj) {
      FragCvt cv;
      cv.u = *(const uint4*)&Bl[(wn + fj * 16 + lm) * 40 + lk];
      bfr[fj] = cv.v;
    }
    #pragma unroll
    for (int fi = 0; fi < 4; ++fi)
      #pragma unroll
      for (int fj = 0; fj < 4; ++fj)
        acc[fi][fj] = __builtin_amdgcn_mfma_f32_16x16x32_bf16(
            af[fi], bfr[fj], acc[fi][fj], 0, 0, 0);
  }

  // ---- store C: col = lane&15, row = (lane>>4)*4 + reg (m89-verified)
  int orow = (l >> 4) * 4;
  #pragma unroll
  for (int fi = 0; fi < 4; ++fi)
    #pragma unroll
    for (int fj = 0; fj < 4; ++fj)
      #pragma unroll
      for (int r = 0; r < 4; ++r)
        Yb[(size_t)(wm + fi * 16 + orow + r) * HW + (wn + fj * 16 + lm)] =
            acc[fi][fj][r];
}

// ---------------------------------------------------------------------------
// depthwise 3x3, SAME zero pad. One block per (channel, batch).
__global__ __launch_bounds__(256) void dwconv_kernel(
    const float* __restrict__ in, size_t in_bstride,
    const float* __restrict__ wdw,
    float* __restrict__ out, size_t out_bstride,
    float* __restrict__ ssq)
{
  int c = blockIdx.x;
  int b = blockIdx.y;
  int t = threadIdx.x;
  int r = t >> 5;
  int xq = t & 31;

  const float4* ip4 = (const float4*)(in + (size_t)b * in_bstride + ((size_t)c << 14));
  float4* op4 = (float4*)(out + (size_t)b * out_bstride + ((size_t)c << 14));
  const float* wp = wdw + c * 9;
  float w0 = wp[0], w1 = wp[1], w2 = wp[2], w3 = wp[3], w4 = wp[4],
        w5 = wp[5], w6 = wp[6], w7 = wp[7], w8 = wp[8];

  const float4 z4 = make_float4(0.f, 0.f, 0.f, 0.f);
  int y0 = r << 4;

  float4 a = (y0 > 0) ? ip4[((y0 - 1) << 5) + xq] : z4;
  float4 bb = ip4[(y0 << 5) + xq];

  float aL = __shfl_up(a.w, 1);  if (xq == 0)  aL = 0.f;
  float aR = __shfl_down(a.x, 1); if (xq == 31) aR = 0.f;
  float bL = __shfl_up(bb.w, 1); if (xq == 0)  bL = 0.f;
  float bR = __shfl_down(bb.x, 1); if (xq == 31) bR = 0.f;

  float ss = 0.f;
  #pragma unroll
  for (int i = 0; i < 16; ++i) {
    int y = y0 + i;
    int yc = (y + 1 < 128) ? (y + 1) : 127;
    float4 cc = ip4[(yc << 5) + xq];
    if (y + 1 >= 128) { cc.x = 0.f; cc.y = 0.f; cc.z = 0.f; cc.w = 0.f; }
    float cL = __shfl_up(cc.w, 1);  if (xq == 0)  cL = 0.f;
    float cR = __shfl_down(cc.x, 1); if (xq == 31) cR = 0.f;

    float4 o;
    o.x = w0 * aL  + w1 * a.x + w2 * a.y +
          w3 * bL  + w4 * bb.x + w5 * bb.y +
          w6 * cL  + w7 * cc.x + w8 * cc.y;
    o.y = w0 * a.x + w1 * a.y + w2 * a.z +
          w3 * bb.x + w4 * bb.y + w5 * bb.z +
          w6 * cc.x + w7 * cc.y + w8 * cc.z;
    o.z = w0 * a.y + w1 * a.z + w2 * a.w +
          w3 * bb.y + w4 * bb.z + w5 * bb.w +
          w6 * cc.y + w7 * cc.z + w8 * cc.w;
    o.w = w0 * a.z + w1 * a.w + w2 * aR +
          w3 * bb.z + w4 * bb.w + w5 * bR +
          w6 * cc.z + w7 * cc.w + w8 * cR;

    op4[(y << 5) + xq] = o;
    ss += o.x * o.x + o.y * o.y + o.z * o.z + o.w * o.w;

    a = bb; aL = bL; aR = bR;
    bb = cc; bL = cL; bR = cR;
  }

  if (ssq) {
    #pragma unroll
    for (int off = 32; off > 0; off >>= 1) ss += __shfl_down(ss, off);
    __shared__ float red[4];
    if ((t & 63) == 0) red[t >> 6] = ss;
    __syncthreads();
    if (t == 0) ssq[b * 256 + c] = red[0] + red[1] + red[2] + red[3];
  }
}

// ---------------------------------------------------------------------------
// S[b,h,c,d] += sum_p qdw[b,h*32+c,p] * kdw[b,h*32+d,p]  (unnormalized Gram)
__global__ __launch_bounds__(256) void gram_kernel(
    const float* __restrict__ qdw, const float* __restrict__ kdw,
    float* __restrict__ S)
{
  int chunk = blockIdx.x, h = blockIdx.y, b = blockIdx.z;
  __shared__ float Qs[32][68];
  __shared__ float Ks[32][68];
  int t = threadIdx.x;
  int wave = t >> 6, lane = t & 63;
  int c0 = lane >> 3, d0 = lane & 7;
  float acc[4][4];
  #pragma unroll
  for (int i = 0; i < 4; ++i)
    #pragma unroll
    for (int j = 0; j < 4; ++j) acc[i][j] = 0.f;

  const float* qb = qdw + (((size_t)b * 256 + h * 32) << 14) + chunk * 1024;
  const float* kb = kdw + (((size_t)b * 256 + h * 32) << 14) + chunk * 1024;
  int lch = t >> 4;
  int lpx = (t & 15) << 2;

  for (int sub = 0; sub < 16; ++sub) {
    float4 qa = *(const float4*)(qb + ((size_t)lch << 14) + sub * 64 + lpx);
    float4 qc = *(const float4*)(qb + ((size_t)(lch + 16) << 14) + sub * 64 + lpx);
    float4 ka = *(const float4*)(kb + ((size_t)lch << 14) + sub * 64 + lpx);
    float4 kc = *(const float4*)(kb + ((size_t)(lch + 16) << 14) + sub * 64 + lpx);
    __syncthreads();
    *(float4*)&Qs[lch][lpx] = qa;
    *(float4*)&Qs[lch + 16][lpx] = qc;
    *(float4*)&Ks[lch][lpx] = ka;
    *(float4*)&Ks[lch + 16][lpx] = kc;
    __syncthreads();
    #pragma unroll
    for (int pg = 0; pg < 4; ++pg) {
      int p0 = (wave << 4) + (pg << 2);
      float4 q0 = *(float4*)&Qs[c0][p0];
      float4 q1 = *(float4*)&Qs[c0 + 8][p0];
      float4 q2 = *(float4*)&Qs[c0 + 16][p0];
      float4 q3 = *(float4*)&Qs[c0 + 24][p0];
      float4 k0v = *(float4*)&Ks[d0][p0];
      float4 k1v = *(float4*)&Ks[d0 + 8][p0];
      float4 k2v = *(float4*)&Ks[d0 + 16][p0];
      float4 k3v = *(float4*)&Ks[d0 + 24][p0];
      float qv[4][4] = {{q0.x, q0.y, q0.z, q0.w}, {q1.x, q1.y, q1.z, q1.w},
                        {q2.x, q2.y, q2.z, q2.w}, {q3.x, q3.y, q3.z, q3.w}};
      float kv[4][4] = {{k0v.x, k0v.y, k0v.z, k0v.w}, {k1v.x, k1v.y, k1v.z, k1v.w},
                        {k2v.x, k2v.y, k2v.z, k2v.w}, {k3v.x, k3v.y, k3v.z, k3v.w}};
      #pragma unroll
      for (int i = 0; i < 4; ++i)
        #pragma unroll
        for (int j = 0; j < 4; ++j)
          acc[i][j] += qv[i][0] * kv[j][0] + qv[i][1] * kv[j][1] +
                       qv[i][2] * kv[j][2] + qv[i][3] * kv[j][3];
    }
  }
  float* Sp = S + (((size_t)b * 8 + h) << 10);
  #pragma unroll
  for (int i = 0; i < 4; ++i)
    #pragma unroll
    for (int j = 0; j < 4; ++j)
      atomicAdd(&Sp[(c0 + 8 * i) * 32 + d0 + 8 * j], acc[i][j]);
}

// ---------------------------------------------------------------------------
// in-place: S <- softmax_d( S / (max(|q|,eps)*max(|k|,eps)) * temp[h] )
__global__ __launch_bounds__(64) void softmax_kernel(
    float* __restrict__ S, const float* __restrict__ ssq,
    const float* __restrict__ ssk, const float* __restrict__ temp)
{
  int bh = blockIdx.x;
  int b = bh >> 3, h = bh & 7;
  int c = threadIdx.x;
  if (c >= 32) return;
  float* row = S + ((size_t)bh << 10) + c * 32;
  float invq = 1.f / fmaxf(sqrtf(ssq[b * 256 + h * 32 + c]), 1e-12f);
  float T = temp[h];
  float lg[32];
  float mx = -1e30f;
  for (int d = 0; d < 32; ++d) {
    float invk = 1.f / fmaxf(sqrtf(ssk[b * 256 + h * 32 + d]), 1e-12f);
    float v = row[d] * invq * invk * T;
    lg[d] = v;
    mx = fmaxf(mx, v);
  }
  float sum = 0.f;
  for (int d = 0; d < 32; ++d) { float e = expf(lg[d] - mx); lg[d] = e; sum += e; }
  float inv = 1.f / sum;
  for (int d = 0; d < 32; ++d) row[d] = lg[d] * inv;
}

// ---------------------------------------------------------------------------
// M[b][o][h*32+d] = sum_c w_proj[o][h*32+c] * attn[b,h,c,d]
__global__ __launch_bounds__(256) void mbuild_kernel(
    const float* __restrict__ attn, const float* __restrict__ wproj,
    float* __restrict__ M)
{
  int o = blockIdx.x, b = blockIdx.y;
  int col = threadIdx.x;
  int h = col >> 5, d = col & 31;
  const float* a = attn + (((size_t)b * 8 + h) << 10);
  const float* wp = wproj + o * 256 + h * 32;
  float s = 0.f;
  #pragma unroll
  for (int cc = 0; cc < 32; ++cc) s += wp[cc] * a[cc * 32 + d];
  M[((size_t)b * 256 + o) * 256 + col] = s;
}

// ---------------------------------------------------------------------------
extern "C" void kernel_launch(void* const* d_in, const int* in_sizes, int n_in,
                              void* d_out, int out_size, void* d_ws, size_t ws_size,
                              hipStream_t stream)
{
  const float* x      = (const float*)d_in[0];
  const float* k_v    = (const float*)d_in[1];
  const float* temp   = (const float*)d_in[2];
  const float* w_kR   = (const float*)d_in[3];
  const float* w_kI   = (const float*)d_in[4];
  const float* w_qR   = (const float*)d_in[5];
  const float* w_qdw  = (const float*)d_in[6];
  const float* w_kvI  = (const float*)d_in[7];
  const float* w_kvdw = (const float*)d_in[8];
  const float* w_proj = (const float*)d_in[9];
  float* out = (float*)d_out;

  float* ws   = (float*)d_ws;
  float* bufA = ws;                 // 64 MB
  float* bufB = ws + 16777216;      // 64 MB
  float* bufC = ws + 33554432;      // 64 MB
  float* sm   = ws + 50331648;      // small region at 192 MB
  float* mod  = sm;                 // 1024
  float* ssq  = sm + 1024;          // 1024 (q norms^2, plain store)
  float* ssk  = sm + 2048;          // 1024 (k norms^2, plain store)
  float* S    = sm + 3072;          // 32768 (Gram -> attn in place)
  float* M    = sm + 3072 + 32768;  // 262144 (fused attn+proj matrix)

  hipMemsetAsync(S, 0, (size_t)32768 * sizeof(float), stream);

  mod_kernel<<<dim3(4), dim3(256), 0, stream>>>(k_v, w_kR, w_kI, mod);

  // k_pre -> bufA ; kdw -> bufB (+ k norms)
  mgemm<<<dim3(128, 2, 4), dim3(256), 0, stream>>>(
      w_kvI, 64, 0, x, 192, 4194304, mod, bufA, 4194304, 64);
  dwconv_kernel<<<dim3(256, 4), dim3(256), 0, stream>>>(
      bufA, 4194304, w_kvdw, bufB, 4194304, ssk);

  // q_pre -> bufA ; qdw -> bufC (+ q norms)
  mgemm<<<dim3(128, 2, 4), dim3(256), 0, stream>>>(
      w_qR, 192, 0, x, 0, 4194304, mod, bufA, 4194304, 192);
  dwconv_kernel<<<dim3(256, 4), dim3(256), 0, stream>>>(
      bufA, 4194304, w_qdw, bufC, 4194304, ssq);

  // Gram: S = qdw . kdw^T over pixels
  gram_kernel<<<dim3(16, 8, 4), dim3(256), 0, stream>>>(bufC, bufB, S);

  // v_pre -> bufA
  mgemm<<<dim3(128, 2, 4), dim3(256), 0, stream>>>(
      w_kvI + 256 * 64, 64, 0, x, 192, 4194304, mod, bufA, 4194304, 64);

  // attn (in place on S), then M = w_proj @ blockdiag(attn)
  softmax_kernel<<<dim3(32), dim3(64), 0, stream>>>(S, ssq, ssk, temp);
  mbuild_kernel<<<dim3(256, 4), dim3(256), 0, stream>>>(S, w_proj, M);

  // vdw -> bufC
  dwconv_kernel<<<dim3(256, 4), dim3(256), 0, stream>>>(
      bufA, 4194304, w_kvdw + 256 * 9, bufC, 4194304, (float*)nullptr);

  // out = M[b] @ vdw[b]
  mgemm<<<dim3(128, 2, 4), dim3(256), 0, stream>>>(
      M, 256, 65536, bufC, 0, 4194304, (const float*)nullptr, out, 4194304, 256);
}